// Round 9
// baseline (762.411 us; speedup 1.0000x reference)
//
#include <hip/hip_runtime.h>
#include <math.h>

#define LN_EPS 1e-5f
#define XS2 264   // padded X row stride in halves (132 dwords ≡ 4 mod 32 banks)

typedef __attribute__((ext_vector_type(8))) _Float16 f16x8;
typedef __attribute__((ext_vector_type(4))) _Float16 f16x4;
typedef __attribute__((ext_vector_type(4))) float f32x4;

__device__ __forceinline__ float sigmoidf(float x) { return 1.0f / (1.0f + expf(-x)); }

__device__ __forceinline__ float wave_sum(float v) {
    v += __shfl_xor(v, 32, 64);
    v += __shfl_xor(v, 16, 64);
    v += __shfl_xor(v, 8, 64);
    v += __shfl_xor(v, 4, 64);
    v += __shfl_xor(v, 2, 64);
    v += __shfl_xor(v, 1, 64);
    return v;
}

// async global->LDS DMA, 16B per lane (wave-uniform lds base, lane i -> +16i)
__device__ __forceinline__ void async_load16(const void* g, void* l) {
    __builtin_amdgcn_global_load_lds(
        (const __attribute__((address_space(1))) void*)g,
        (__attribute__((address_space(3))) void*)l, 16, 0, 0);
}

// ---------------------------------------------------------------------------
// x [B,Cin,HW] fp32 -> xT hi/lo fp16 planes [B,HW,Cin]. 32x32 LDS tile.
// Grid (HW/32, Cin/32, B), block 256.
// ---------------------------------------------------------------------------
__global__ __launch_bounds__(256) void transpose_split_x(
    const float* __restrict__ x,
    _Float16* __restrict__ xh, _Float16* __restrict__ xm,
    int Cin, int HW)
{
    __shared__ float T[32][33];
    const int p0 = blockIdx.x * 32, c0 = blockIdx.y * 32, b = blockIdx.z;
    const int t = threadIdx.x;
    const int pl = t & 31, cl = t >> 5;
    const float* xb = x + (size_t)b * Cin * HW;
#pragma unroll
    for (int rep = 0; rep < 4; rep++)
        T[cl + rep * 8][pl] = xb[(size_t)(c0 + cl + rep * 8) * HW + p0 + pl];
    __syncthreads();
    const int cl2 = t & 31, pl2 = t >> 5;
#pragma unroll
    for (int rep = 0; rep < 4; rep++) {
        const float v = T[cl2][pl2 + rep * 8];
        const _Float16 h = (_Float16)v;
        const _Float16 m = (_Float16)(v - (float)h);
        const size_t o = ((size_t)b * HW + p0 + pl2 + rep * 8) * Cin + c0 + cl2;
        xh[o] = h;
        xm[o] = m;
    }
}

// ---------------------------------------------------------------------------
// Lateral weights lw [256][Cin] (o-major) -> hi/lo fp16 fragment-packed:
// frag g = ks*16+nt, plane p in {0,1}: f16x8 unit (g*2+p)*64+lane, lane holds
// B[k=ks*32+(lane>>4)*8+j][n=nt*16+(lane&15)]. Grid (Cin/32)*16/4 x 256.
// ---------------------------------------------------------------------------
__global__ __launch_bounds__(256) void prep_latw(
    const float* __restrict__ lw, _Float16* __restrict__ Wpk, int Cin)
{
    const int t = threadIdx.x;
    const int g = blockIdx.x * 4 + (t >> 6);
    const int lane = t & 63;
    const int nt = g & 15, ks = g >> 4;
    const int n = nt * 16 + (lane & 15);
    const int k0 = ks * 32 + (lane >> 4) * 8;
    _Float16 h[8], m[8];
#pragma unroll
    for (int j = 0; j < 8; j++) {
        const float f = lw[(size_t)n * Cin + k0 + j];
        h[j] = (_Float16)f;
        m[j] = (_Float16)(f - (float)h[j]);
    }
    const size_t oh = ((size_t)(g * 2 + 0) * 64 + lane) * 8;
    const size_t om = ((size_t)(g * 2 + 1) * 64 + lane) * 8;
#pragma unroll
    for (int j = 0; j < 8; j++) { Wpk[oh + j] = h[j]; Wpk[om + j] = m[j]; }
}

// ---------------------------------------------------------------------------
// Split [4][256][256] (k-major) loc weights into hi/lo fp16 fragment-packed.
// frag g=(l*8+ks)*16+nt. Grid 128 x 256.
// ---------------------------------------------------------------------------
__global__ __launch_bounds__(256) void prep_wfrag16(
    const float* __restrict__ W, _Float16* __restrict__ Wpk)
{
    const int t = threadIdx.x;
    const int g = blockIdx.x * 4 + (t >> 6);
    const int lane = t & 63;
    const int nt = g & 15, ks = (g >> 4) & 7, l = g >> 7;
    const int n = nt * 16 + (lane & 15);
    const int k0 = ks * 32 + (lane >> 4) * 8;
    _Float16 h[8], m[8];
#pragma unroll
    for (int j = 0; j < 8; j++) {
        const float f = W[(size_t)l * 65536 + (size_t)(k0 + j) * 256 + n];
        h[j] = (_Float16)f;
        m[j] = (_Float16)(f - (float)h[j]);
    }
    const size_t oh = ((size_t)(g * 2 + 0) * 64 + lane) * 8;
    const size_t om = ((size_t)(g * 2 + 1) * 64 + lane) * 8;
#pragma unroll
    for (int j = 0; j < 8; j++) { Wpk[oh + j] = h[j]; Wpk[om + j] = m[j]; }
}

// ---------------------------------------------------------------------------
// Lateral conv + BN via fp16x2 MFMA. One launch for all 3 levels.
// Block = 512 thr (8 waves), tile M=64 pixels x N=256 outs; wave w owns cols
// [w*32, w*32+32). A-fragments straight from global xT (16B/lane); no LDS.
// Grid: B*64 + B*16 + B*4 blocks.
// ---------------------------------------------------------------------------
__global__ __launch_bounds__(512) void lateral_mfma(
    const _Float16* __restrict__ xh3, const _Float16* __restrict__ xm3,
    const _Float16* __restrict__ xh4, const _Float16* __restrict__ xm4,
    const _Float16* __restrict__ xh5, const _Float16* __restrict__ xm5,
    const _Float16* __restrict__ w3, const _Float16* __restrict__ w4,
    const _Float16* __restrict__ w5,
    const float* __restrict__ bng, const float* __restrict__ bnb,
    const float* __restrict__ bnm, const float* __restrict__ bnv,
    float* __restrict__ flat, int B)
{
    const int bid = blockIdx.x;
    const int n3 = B * 64, n4 = B * 16;
    const _Float16 *xh, *xm, *wp;
    int CH, HW, base, rb, lv;
    if (bid < n3)            { xh = xh3; xm = xm3; wp = w3; CH = 8;  HW = 4096; base = 0;    rb = bid * 64;              lv = 0; }
    else if (bid < n3 + n4)  { xh = xh4; xm = xm4; wp = w4; CH = 16; HW = 1024; base = 4096; rb = (bid - n3) * 64;       lv = 1; }
    else                     { xh = xh5; xm = xm5; wp = w5; CH = 32; HW = 256;  base = 5120; rb = (bid - n3 - n4) * 64;  lv = 2; }
    const int Cin = CH * 32;
    const int b   = rb / HW;
    const int px0 = rb % HW;

    const int t = threadIdx.x, lane = t & 63, w = t >> 6;
    const int ar = lane & 15, quad = lane >> 4;
    const f16x8* BP = (const f16x8*)wp;

    f32x4 acc[4][2];
#pragma unroll
    for (int mt = 0; mt < 4; mt++)
#pragma unroll
        for (int q = 0; q < 2; q++) acc[mt][q] = (f32x4){0.f, 0.f, 0.f, 0.f};

    for (int ks = 0; ks < CH; ks++) {
        const int ao = ks * 32 + quad * 8;
        f16x8 bh[2], bm[2];
#pragma unroll
        for (int q = 0; q < 2; q++) {
            const int g = ks * 16 + (w * 2 + q);
            bh[q] = BP[(g * 2 + 0) * 64 + lane];
            bm[q] = BP[(g * 2 + 1) * 64 + lane];
        }
        f16x8 ah[4], am[4];
#pragma unroll
        for (int mt = 0; mt < 4; mt++) {
            const size_t off = (size_t)(rb + ar + mt * 16) * Cin + ao;
            ah[mt] = *(const f16x8*)&xh[off];
            am[mt] = *(const f16x8*)&xm[off];
        }
#pragma unroll
        for (int q = 0; q < 2; q++)
#pragma unroll
            for (int mt = 0; mt < 4; mt++)
                acc[mt][q] = __builtin_amdgcn_mfma_f32_16x16x32_f16(ah[mt], bh[q], acc[mt][q], 0, 0, 0);
#pragma unroll
        for (int q = 0; q < 2; q++)
#pragma unroll
            for (int mt = 0; mt < 4; mt++)
                acc[mt][q] = __builtin_amdgcn_mfma_f32_16x16x32_f16(ah[mt], bm[q], acc[mt][q], 0, 0, 0);
#pragma unroll
        for (int q = 0; q < 2; q++)
#pragma unroll
            for (int mt = 0; mt < 4; mt++)
                acc[mt][q] = __builtin_amdgcn_mfma_f32_16x16x32_f16(am[mt], bh[q], acc[mt][q], 0, 0, 0);
#pragma unroll
        for (int q = 0; q < 2; q++)
#pragma unroll
            for (int mt = 0; mt < 4; mt++)
                acc[mt][q] = __builtin_amdgcn_mfma_f32_16x16x32_f16(am[mt], bm[q], acc[mt][q], 0, 0, 0);
    }

    // BN epilogue + write flat (fp32)
#pragma unroll
    for (int q = 0; q < 2; q++) {
        const int col = (w * 2 + q) * 16 + ar;
        const float sc = bng[lv * 256 + col] * rsqrtf(bnv[lv * 256 + col] + LN_EPS);
        const float mh = bnm[lv * 256 + col];
        const float bb = bnb[lv * 256 + col];
#pragma unroll
        for (int mt = 0; mt < 4; mt++)
#pragma unroll
            for (int r = 0; r < 4; r++) {
                const int lr = mt * 16 + quad * 4 + r;
                flat[((size_t)b * 5376 + base + px0 + lr) * 256 + col] =
                    (acc[mt][q][r] - mh) * sc + bb;
            }
    }
}

// ---------------------------------------------------------------------------
// Fused loc MLP (fp16x2 MFMA, 4 products): 4 layers + 256->1 projection.
// Grid M/64, block 512 (8 waves). LDS ~71.7KB -> 2 blocks/CU.
// ---------------------------------------------------------------------------
__global__ __launch_bounds__(512) void loc_mlp_f16(
    const float* __restrict__ Xin,
    const _Float16* __restrict__ Wpk,
    const float* __restrict__ bs, const float* __restrict__ lng,
    const float* __restrict__ lnb, const float* __restrict__ Wf,
    const float* __restrict__ bfp, float* __restrict__ logits)
{
    __shared__ _Float16 Xh[64 * XS2];
    __shared__ _Float16 Xm[64 * XS2];
    __shared__ float red[2 * 64 * 8];    // [plane][row][wave]
    const int t = threadIdx.x, lane = t & 63, w = t >> 6;
    const int r0 = blockIdx.x * 64;
    const f16x8* BP = (const f16x8*)Wpk;

    // stage 64x256 fp32 -> hi/lo fp16 planes (nontemporal: stream)
    const float* Xg = Xin + (size_t)r0 * 256;
#pragma unroll
    for (int i = 0; i < 8; i++) {
        const int f = i * 2048 + t * 4;
        const int row = f >> 8, col = f & 255;
        const f32x4 v = __builtin_nontemporal_load((const f32x4*)&Xg[f]);
        f16x4 h, m;
        h[0] = (_Float16)v[0]; m[0] = (_Float16)(v[0] - (float)h[0]);
        h[1] = (_Float16)v[1]; m[1] = (_Float16)(v[1] - (float)h[1]);
        h[2] = (_Float16)v[2]; m[2] = (_Float16)(v[2] - (float)h[2]);
        h[3] = (_Float16)v[3]; m[3] = (_Float16)(v[3] - (float)h[3]);
        *(f16x4*)&Xh[row * XS2 + col] = h;
        *(f16x4*)&Xm[row * XS2 + col] = m;
    }

    f32x4 acc[4][2];
    float mean[4][4], rstd[4][4];
    const int ar = lane & 15, quad = lane >> 4;

    for (int l = 0; l < 4; l++) {
        __syncthreads();                      // X planes ready
#pragma unroll
        for (int mt = 0; mt < 4; mt++)
#pragma unroll
            for (int q = 0; q < 2; q++) acc[mt][q] = (f32x4){0.f, 0.f, 0.f, 0.f};
#pragma unroll
        for (int ks = 0; ks < 8; ks++) {
            const int ao = ks * 32 + quad * 8;
            f16x8 bh[2], bm[2];
#pragma unroll
            for (int q = 0; q < 2; q++) {
                const int g = (l * 8 + ks) * 16 + (w * 2 + q);
                bh[q] = BP[(g * 2 + 0) * 64 + lane];
                bm[q] = BP[(g * 2 + 1) * 64 + lane];
            }
            f16x8 ah[4], am[4];
#pragma unroll
            for (int mt = 0; mt < 4; mt++) {
                ah[mt] = *(const f16x8*)&Xh[(ar + mt * 16) * XS2 + ao];
                am[mt] = *(const f16x8*)&Xm[(ar + mt * 16) * XS2 + ao];
            }
#pragma unroll
            for (int q = 0; q < 2; q++)
#pragma unroll
                for (int mt = 0; mt < 4; mt++)
                    acc[mt][q] = __builtin_amdgcn_mfma_f32_16x16x32_f16(ah[mt], bh[q], acc[mt][q], 0, 0, 0);
#pragma unroll
            for (int q = 0; q < 2; q++)
#pragma unroll
                for (int mt = 0; mt < 4; mt++)
                    acc[mt][q] = __builtin_amdgcn_mfma_f32_16x16x32_f16(ah[mt], bm[q], acc[mt][q], 0, 0, 0);
#pragma unroll
            for (int q = 0; q < 2; q++)
#pragma unroll
                for (int mt = 0; mt < 4; mt++)
                    acc[mt][q] = __builtin_amdgcn_mfma_f32_16x16x32_f16(am[mt], bh[q], acc[mt][q], 0, 0, 0);
#pragma unroll
            for (int q = 0; q < 2; q++)
#pragma unroll
                for (int mt = 0; mt < 4; mt++)
                    acc[mt][q] = __builtin_amdgcn_mfma_f32_16x16x32_f16(am[mt], bm[q], acc[mt][q], 0, 0, 0);
        }

        // ---- bias + LN stats (cross-wave over 8 col-waves) ----
        float bcol[2];
#pragma unroll
        for (int q = 0; q < 2; q++) bcol[q] = bs[l * 256 + (w * 2 + q) * 16 + ar];
#pragma unroll
        for (int mt = 0; mt < 4; mt++)
#pragma unroll
            for (int q = 0; q < 2; q++)
#pragma unroll
                for (int r = 0; r < 4; r++) acc[mt][q][r] += bcol[q];

#pragma unroll
        for (int mt = 0; mt < 4; mt++)
#pragma unroll
            for (int r = 0; r < 4; r++) {
                float s  = acc[mt][0][r] + acc[mt][1][r];
                float ss = acc[mt][0][r] * acc[mt][0][r] + acc[mt][1][r] * acc[mt][1][r];
#pragma unroll
                for (int off = 1; off < 16; off <<= 1) {
                    s  += __shfl_xor(s, off, 64);
                    ss += __shfl_xor(ss, off, 64);
                }
                if (ar == 0) {
                    const int row = mt * 16 + quad * 4 + r;
                    red[row * 8 + w] = s;
                    red[512 + row * 8 + w] = ss;
                }
            }
        __syncthreads();
#pragma unroll
        for (int mt = 0; mt < 4; mt++)
#pragma unroll
            for (int r = 0; r < 4; r++) {
                const int row = mt * 16 + quad * 4 + r;
                float s = 0.f, ss = 0.f;
#pragma unroll
                for (int q = 0; q < 8; q++) { s += red[row * 8 + q]; ss += red[512 + row * 8 + q]; }
                const float mn = s * (1.0f / 256.0f);
                mean[mt][r] = mn;
                rstd[mt][r] = rsqrtf(ss * (1.0f / 256.0f) - mn * mn + LN_EPS);
            }

        if (l < 3) {
#pragma unroll
            for (int q = 0; q < 2; q++) {
                const int col = (w * 2 + q) * 16 + ar;
                const float gc = lng[l * 256 + col], bc = lnb[l * 256 + col];
#pragma unroll
                for (int mt = 0; mt < 4; mt++)
#pragma unroll
                    for (int r = 0; r < 4; r++) {
                        const int row = mt * 16 + quad * 4 + r;
                        float v = (acc[mt][q][r] - mean[mt][r]) * rstd[mt][r] * gc + bc;
                        v = v * sigmoidf(v);
                        const _Float16 h = (_Float16)v;
                        Xh[row * XS2 + col] = h;
                        Xm[row * XS2 + col] = (_Float16)(v - (float)h);
                    }
            }
        } else {
            float p[4][4];
#pragma unroll
            for (int mt = 0; mt < 4; mt++)
#pragma unroll
                for (int r = 0; r < 4; r++) p[mt][r] = 0.0f;
#pragma unroll
            for (int q = 0; q < 2; q++) {
                const int col = (w * 2 + q) * 16 + ar;
                const float gc = lng[3 * 256 + col], bc = lnb[3 * 256 + col];
                const float wf = Wf[col];
#pragma unroll
                for (int mt = 0; mt < 4; mt++)
#pragma unroll
                    for (int r = 0; r < 4; r++) {
                        float v = (acc[mt][q][r] - mean[mt][r]) * rstd[mt][r] * gc + bc;
                        p[mt][r] += (v * sigmoidf(v)) * wf;
                    }
            }
            __syncthreads();
#pragma unroll
            for (int mt = 0; mt < 4; mt++)
#pragma unroll
                for (int r = 0; r < 4; r++) {
                    float s = p[mt][r];
#pragma unroll
                    for (int off = 1; off < 16; off <<= 1) s += __shfl_xor(s, off, 64);
                    if (ar == 0) red[(mt * 16 + quad * 4 + r) * 8 + w] = s;
                }
            __syncthreads();
            if (t < 64) {
                float s = 0.f;
#pragma unroll
                for (int q = 0; q < 8; q++) s += red[t * 8 + q];
                logits[r0 + t] = s + bfp[0];
            }
        }
    }
}

// ---------------------------------------------------------------------------
// Top-100 per batch (sorted desc, ties -> lower index). Grid B, block 256.
// ---------------------------------------------------------------------------
__global__ __launch_bounds__(256) void topk_kernel(
    const float* __restrict__ logits, int* __restrict__ idx_out,
    float* __restrict__ out, int B)
{
    __shared__ float v[5376];
    __shared__ float wv_s[4];
    __shared__ int wi_s[4];

    const int t = threadIdx.x, b = blockIdx.x;
    const int lane = t & 63, w = t >> 6;

    for (int i = t; i < 5376; i += 256) v[i] = logits[b * 5376 + i];
    __syncthreads();

    int cnt = 0;
    for (int k = 0; k < 100; k++) {
        float bv = -1e30f;
        int bi = 0x7fffffff;
        for (int i = t; i < 5376; i += 256) {
            const float val = v[i];
            if (val > bv) { bv = val; bi = i; }
        }
#pragma unroll
        for (int off = 32; off > 0; off >>= 1) {
            const float ov = __shfl_xor(bv, off, 64);
            const int oi = __shfl_xor(bi, off, 64);
            if (ov > bv || (ov == bv && oi < bi)) { bv = ov; bi = oi; }
        }
        if (lane == 0) { wv_s[w] = bv; wi_s[w] = bi; }
        __syncthreads();
        if (t == 0) {
            float fb = wv_s[0]; int fi = wi_s[0];
            for (int q = 1; q < 4; q++)
                if (wv_s[q] > fb || (wv_s[q] == fb && wi_s[q] < fi)) { fb = wv_s[q]; fi = wi_s[q]; }
            v[fi] = -1e30f;
            idx_out[b * 100 + k] = fi;
            out[B + b * 100 + k] = sigmoidf(fb);
            if (fb > 0.0f) cnt++;
        }
        __syncthreads();
    }
    if (t == 0) out[b] = (float)cnt;
}

// ---------------------------------------------------------------------------
// fp32 GEMM+bias+LN-stats on the wave-private 32x256 LDS tile (R3 core).
// ---------------------------------------------------------------------------
__device__ __forceinline__ void gemm8_pipelined(
    const float* __restrict__ Wg, const float* __restrict__ bias,
    float* X, float (*Wbuf)[8 * 256], int t,
    float acc[8][4], float mean[8], float rstd[8])
{
    const int lane = t & 63, w = t >> 6;
#pragma unroll
    for (int mi = 0; mi < 8; mi++)
#pragma unroll
        for (int c = 0; c < 4; c++) acc[mi][c] = 0.0f;

#pragma unroll
    for (int i = 0; i < 2; i++) {
        const int q = w * 2 + i;
        async_load16(&Wg[(size_t)q * 256 + lane * 4], &Wbuf[0][q * 256]);
    }

    for (int ch = 0; ch < 32; ch++) {
        __syncthreads();
        if (ch + 1 < 32) {
#pragma unroll
            for (int i = 0; i < 2; i++) {
                const int q = w * 2 + i;
                async_load16(&Wg[(size_t)((ch + 1) * 8 + q) * 256 + lane * 4],
                             &Wbuf[(ch + 1) & 1][q * 256]);
            }
        }
        const float* Wb = Wbuf[ch & 1];
#pragma unroll
        for (int k4 = 0; k4 < 2; k4++) {
            float4 xq[8];
#pragma unroll
            for (int mi = 0; mi < 8; mi++)
                xq[mi] = *(const float4*)&X[(w * 8 + mi) * 256 + ch * 8 + k4 * 4];
#pragma unroll
            for (int j = 0; j < 4; j++) {
                const float4 wv = *(const float4*)&Wb[(k4 * 4 + j) * 256 + lane * 4];
#pragma unroll
                for (int mi = 0; mi < 8; mi++) {
                    const float xs = (j == 0) ? xq[mi].x : (j == 1) ? xq[mi].y
                                   : (j == 2) ? xq[mi].z : xq[mi].w;
                    acc[mi][0] += xs * wv.x;
                    acc[mi][1] += xs * wv.y;
                    acc[mi][2] += xs * wv.z;
                    acc[mi][3] += xs * wv.w;
                }
            }
        }
    }

    const int o = lane * 4;
    const float4 bv = *(const float4*)&bias[o];
#pragma unroll
    for (int mi = 0; mi < 8; mi++) {
        acc[mi][0] += bv.x; acc[mi][1] += bv.y; acc[mi][2] += bv.z; acc[mi][3] += bv.w;
        float s  = acc[mi][0] + acc[mi][1] + acc[mi][2] + acc[mi][3];
        float ss = acc[mi][0] * acc[mi][0] + acc[mi][1] * acc[mi][1] +
                   acc[mi][2] * acc[mi][2] + acc[mi][3] * acc[mi][3];
        s  = wave_sum(s);
        ss = wave_sum(ss);
        const float m = s * (1.0f / 256.0f);
        mean[mi] = m;
        rstd[mi] = rsqrtf(ss * (1.0f / 256.0f) - m * m + LN_EPS);
    }
}

// ---------------------------------------------------------------------------
// Fused heads (fp32, proven): gather + 4 layers + finals. Grid (25,2).
// ---------------------------------------------------------------------------
__global__ __launch_bounds__(256) void heads_mlp(
    const float* __restrict__ flat, const int* __restrict__ idxb,
    const float* __restrict__ cWs, const float* __restrict__ cbs,
    const float* __restrict__ cg, const float* __restrict__ cb,
    const float* __restrict__ cWf, const float* __restrict__ cbf,
    const float* __restrict__ xWs, const float* __restrict__ xbs,
    const float* __restrict__ xg, const float* __restrict__ xb_,
    const float* __restrict__ xWf, const float* __restrict__ xbf,
    const int* __restrict__ full_h, const int* __restrict__ full_w,
    float* __restrict__ out, int B)
{
    __shared__ float X[32 * 256];
    __shared__ float Wbuf[2][8 * 256];
    const int head = blockIdx.y;
    const float* Ws  = head ? xWs : cWs;
    const float* bsv = head ? xbs : cbs;
    const float* gv_ = head ? xg  : cg;
    const float* bv_ = head ? xb_ : cb;

    const int t = threadIdx.x, lane = t & 63, w = t >> 6;
    const int r0 = blockIdx.x * 32;

#pragma unroll
    for (int i = 0; i < 8; i++) {
        const int r = r0 + w * 8 + i;
        const int n = idxb[r];
        const int b = r / 100;
        *(float4*)&X[(w * 8 + i) * 256 + lane * 4] =
            *(const float4*)&flat[((size_t)b * 5376 + n) * 256 + lane * 4];
    }

    float acc[8][4], mean[8], rstd[8];
    for (int l = 0; l < 4; l++) {
        gemm8_pipelined(Ws + l * 65536, bsv + l * 256, X, Wbuf, t, acc, mean, rstd);
        const int o = lane * 4;
        const float4 gvv = *(const float4*)&gv_[l * 256 + o];
        const float4 bvv = *(const float4*)&bv_[l * 256 + o];
        const float gl[4] = {gvv.x, gvv.y, gvv.z, gvv.w};
        const float bl[4] = {bvv.x, bvv.y, bvv.z, bvv.w};
#pragma unroll
        for (int mi = 0; mi < 8; mi++) {
            float4 outv;
            float v0 = (acc[mi][0] - mean[mi]) * rstd[mi] * gl[0] + bl[0];
            float v1 = (acc[mi][1] - mean[mi]) * rstd[mi] * gl[1] + bl[1];
            float v2 = (acc[mi][2] - mean[mi]) * rstd[mi] * gl[2] + bl[2];
            float v3 = (acc[mi][3] - mean[mi]) * rstd[mi] * gl[3] + bl[3];
            outv.x = v0 * sigmoidf(v0); outv.y = v1 * sigmoidf(v1);
            outv.z = v2 * sigmoidf(v2); outv.w = v3 * sigmoidf(v3);
            *(float4*)&X[(w * 8 + mi) * 256 + o] = outv;
        }
    }
    __syncthreads();

    const int m = t >> 3, g = t & 7;
    if (head == 0) {
        const int jbase = g * 10;
        float lg[10];
#pragma unroll
        for (int jj = 0; jj < 10; jj++) lg[jj] = cbf[jbase + jj];
        for (int k = 0; k < 256; k++) {
            const float hv = X[m * 256 + k];
            const float* wr = &cWf[k * 80 + jbase];
#pragma unroll
            for (int jj = 0; jj < 10; jj++) lg[jj] += hv * wr[jj];
        }
        float best = lg[0]; int bj = jbase;
#pragma unroll
        for (int jj = 1; jj < 10; jj++)
            if (lg[jj] > best) { best = lg[jj]; bj = jbase + jj; }
#pragma unroll
        for (int off = 1; off < 8; off <<= 1) {
            const float ob = __shfl_xor(best, off, 64);
            const int oj = __shfl_xor(bj, off, 64);
            if (ob > best || (ob == best && oj < bj)) { best = ob; bj = oj; }
        }
        if (g == 0) out[B + B * 100 + r0 + m] = (float)bj;
    } else {
        float a[4] = {0.f, 0.f, 0.f, 0.f};
#pragma unroll
        for (int k4 = 0; k4 < 8; k4++) {
            const float4 hv = *(const float4*)&X[m * 256 + g * 32 + k4 * 4];
            const float h4[4] = {hv.x, hv.y, hv.z, hv.w};
#pragma unroll
            for (int j = 0; j < 4; j++) {
                const int k = g * 32 + k4 * 4 + j;
                const float4 wf = *(const float4*)&xWf[k * 4];
                a[0] += h4[j] * wf.x; a[1] += h4[j] * wf.y;
                a[2] += h4[j] * wf.z; a[3] += h4[j] * wf.w;
            }
        }
#pragma unroll
        for (int off = 1; off < 8; off <<= 1) {
            a[0] += __shfl_xor(a[0], off, 64);
            a[1] += __shfl_xor(a[1], off, 64);
            a[2] += __shfl_xor(a[2], off, 64);
            a[3] += __shfl_xor(a[3], off, 64);
        }
        if (g == 0) {
            const int r = r0 + m;
            const float e0 = a[0] + xbf[0], e1 = a[1] + xbf[1];
            const float e2 = a[2] + xbf[2], e3 = a[3] + xbf[3];
            const int n = idxb[r];
            int base, gw, gh;
            if (n < 4096)      { base = 0;    gw = 64; gh = 64; }
            else if (n < 5120) { base = 4096; gw = 32; gh = 32; }
            else               { base = 5120; gw = 16; gh = 16; }
            const int p = n - base;
            const int py = p / gw, px = p % gw;
            const float gx = (px + 0.5f) / gw;
            const float gy = (py + 0.5f) / gh;
            const float fw = (float)full_w[0], fh = (float)full_h[0];
            const int ob = B + 2 * B * 100;
            out[ob + r * 4 + 0] = (gx - 0.5f / gw * expf(e0)) * fw;
            out[ob + r * 4 + 1] = (gy - 0.5f / gh * expf(e1)) * fh;
            out[ob + r * 4 + 2] = (gx + 0.5f / gw * expf(e2)) * fw;
            out[ob + r * 4 + 3] = (gy + 0.5f / gh * expf(e3)) * fh;
        }
    }
}

extern "C" void kernel_launch(void* const* d_in, const int* in_sizes, int n_in,
                              void* d_out, int out_size, void* d_ws, size_t ws_size,
                              hipStream_t stream)
{
    const float* x3  = (const float*)d_in[0];
    const float* x4  = (const float*)d_in[1];
    const float* x5  = (const float*)d_in[2];
    const float* lw3 = (const float*)d_in[3];
    const float* lw4 = (const float*)d_in[4];
    const float* lw5 = (const float*)d_in[5];
    const float* bng = (const float*)d_in[6];
    const float* bnb = (const float*)d_in[7];
    const float* bnm = (const float*)d_in[8];
    const float* bnv = (const float*)d_in[9];

    const float* loc_Ws  = (const float*)d_in[10];
    const float* loc_bs  = (const float*)d_in[11];
    const float* loc_lng = (const float*)d_in[12];
    const float* loc_lnb = (const float*)d_in[13];
    const float* loc_Wf  = (const float*)d_in[14];
    const float* loc_bf  = (const float*)d_in[15];

    const float* cls_Ws  = (const float*)d_in[16];
    const float* cls_bs  = (const float*)d_in[17];
    const float* cls_lng = (const float*)d_in[18];
    const float* cls_lnb = (const float*)d_in[19];
    const float* cls_Wf  = (const float*)d_in[20];
    const float* cls_bf  = (const float*)d_in[21];

    const float* box_Ws  = (const float*)d_in[22];
    const float* box_bs  = (const float*)d_in[23];
    const float* box_lng = (const float*)d_in[24];
    const float* box_lnb = (const float*)d_in[25];
    const float* box_Wf  = (const float*)d_in[26];
    const float* box_bf  = (const float*)d_in[27];

    const int* full_h = (const int*)d_in[28];
    const int* full_w = (const int*)d_in[29];

    const int B = in_sizes[0] / (256 * 64 * 64);   // 8
    const int M = B * 5376;                        // 43008

    float* ws = (float*)d_ws;
    float* flat = ws;                                  // [M*256] fp32
    float* loc  = flat + (size_t)M * 256;              // [M]
    int*   idxb = (int*)(loc + M);                     // [B*100] (padded 1024)
    _Float16* locWpk = (_Float16*)(idxb + 1024);       // 1 MB
    _Float16* xh3 = locWpk + 524288;                   // B*4096*256 halves
    _Float16* xm3 = xh3 + (size_t)B * 4096 * 256;
    _Float16* xh4 = xm3 + (size_t)B * 4096 * 256;      // B*1024*512
    _Float16* xm4 = xh4 + (size_t)B * 1024 * 512;
    _Float16* xh5 = xm4 + (size_t)B * 1024 * 512;      // B*256*1024
    _Float16* xm5 = xh5 + (size_t)B * 256 * 1024;
    _Float16* w3  = xm5 + (size_t)B * 256 * 1024;      // 8*16 frags *1024 halves
    _Float16* w4  = w3 + 131072;
    _Float16* w5  = w4 + 262144;

    float* out = (float*)d_out;
    const dim3 blk(256);

    // 0) weight & activation preprocessing
    prep_latw<<<(256 / 32) * 16 / 4, blk, 0, stream>>>(lw3, w3, 256);
    prep_latw<<<(512 / 32) * 16 / 4, blk, 0, stream>>>(lw4, w4, 512);
    prep_latw<<<(1024 / 32) * 16 / 4, blk, 0, stream>>>(lw5, w5, 1024);
    prep_wfrag16<<<128, blk, 0, stream>>>(loc_Ws, locWpk);
    transpose_split_x<<<dim3(4096 / 32, 256 / 32, B), blk, 0, stream>>>(x3, xh3, xm3, 256, 4096);
    transpose_split_x<<<dim3(1024 / 32, 512 / 32, B), blk, 0, stream>>>(x4, xh4, xm4, 512, 1024);
    transpose_split_x<<<dim3(256 / 32, 1024 / 32, B), blk, 0, stream>>>(x5, xh5, xm5, 1024, 256);

    // 1) laterals (fp16x2 MFMA) -> flat
    lateral_mfma<<<B * 64 + B * 16 + B * 4, dim3(512), 0, stream>>>(
        xh3, xm3, xh4, xm4, xh5, xm5, w3, w4, w5,
        bng, bnb, bnm, bnv, flat, B);

    // 2) fused loc MLP (fp16x2 MFMA) -> logits
    loc_mlp_f16<<<M / 64, dim3(512), 0, stream>>>(flat, locWpk, loc_bs,
                                                  loc_lng, loc_lnb, loc_Wf, loc_bf, loc);

    // 3) top-k
    topk_kernel<<<B, blk, 0, stream>>>(loc, idxb, out, B);

    // 4) both heads (fp32, proven)
    heads_mlp<<<dim3((B * 100) / 32, 2), blk, 0, stream>>>(
        flat, idxb,
        cls_Ws, cls_bs, cls_lng, cls_lnb, cls_Wf, cls_bf,
        box_Ws, box_bs, box_lng, box_lnb, box_Wf, box_bf,
        full_h, full_w, out, B);
}

// Round 10
// 673.944 us; speedup vs baseline: 1.1313x; 1.1313x over previous
//
#include <hip/hip_runtime.h>
#include <math.h>

#define LN_EPS 1e-5f
#define XS2 264   // padded X row stride in halves (132 dwords ≡ 4 mod 32 banks)

typedef __attribute__((ext_vector_type(8))) _Float16 f16x8;
typedef __attribute__((ext_vector_type(4))) _Float16 f16x4;
typedef __attribute__((ext_vector_type(4))) float f32x4;

__device__ __forceinline__ float sigmoidf(float x) { return 1.0f / (1.0f + expf(-x)); }
// fast silu-grade sigmoid: v_exp + v_rcp, ~1e-7 rel err (<< fp16x2 noise floor)
__device__ __forceinline__ float sigmoid_fast(float x) {
    return __builtin_amdgcn_rcpf(1.0f + __expf(-x));
}

// ---------------------------------------------------------------------------
// Fused weight prep: loc/cls/box MLP stacks + 3 lateral weights -> hi/lo fp16
// fragment-packed (frag g, plane p: f16x8 unit (g*2+p)*64+lane).
// MLP stacks: g=(l*8+ks)*16+nt, 512 groups each. Laterals: g=ks*16+nt.
// Grid 608 x 256 (2432 groups).
// ---------------------------------------------------------------------------
__global__ __launch_bounds__(256) void prep_all(
    const float* __restrict__ locW, const float* __restrict__ clsW,
    const float* __restrict__ boxW,
    const float* __restrict__ lw3, const float* __restrict__ lw4,
    const float* __restrict__ lw5,
    _Float16* __restrict__ locP, _Float16* __restrict__ clsP,
    _Float16* __restrict__ boxP,
    _Float16* __restrict__ w3, _Float16* __restrict__ w4,
    _Float16* __restrict__ w5)
{
    const int t = threadIdx.x, lane = t & 63;
    const int gi = blockIdx.x * 4 + (t >> 6);
    const float* W; _Float16* P; int g, Cin = 0; bool mlp;
    if (gi < 512)        { W = locW; P = locP; g = gi;        mlp = true; }
    else if (gi < 1024)  { W = clsW; P = clsP; g = gi - 512;  mlp = true; }
    else if (gi < 1536)  { W = boxW; P = boxP; g = gi - 1024; mlp = true; }
    else if (gi < 1664)  { W = lw3;  P = w3;   g = gi - 1536; mlp = false; Cin = 256; }
    else if (gi < 1920)  { W = lw4;  P = w4;   g = gi - 1664; mlp = false; Cin = 512; }
    else                 { W = lw5;  P = w5;   g = gi - 1920; mlp = false; Cin = 1024; }

    _Float16 h[8], m[8];
    if (mlp) {
        const int nt = g & 15, ks = (g >> 4) & 7, l = g >> 7;
        const int n = nt * 16 + (lane & 15);
        const int k0 = ks * 32 + (lane >> 4) * 8;
#pragma unroll
        for (int j = 0; j < 8; j++) {
            const float f = W[(size_t)l * 65536 + (size_t)(k0 + j) * 256 + n];
            h[j] = (_Float16)f;
            m[j] = (_Float16)(f - (float)h[j]);
        }
    } else {
        const int nt = g & 15, ks = g >> 4;
        const int n = nt * 16 + (lane & 15);
        const int k0 = ks * 32 + (lane >> 4) * 8;
#pragma unroll
        for (int j = 0; j < 8; j++) {
            const float f = W[(size_t)n * Cin + k0 + j];
            h[j] = (_Float16)f;
            m[j] = (_Float16)(f - (float)h[j]);
        }
    }
    const size_t oh = ((size_t)(g * 2 + 0) * 64 + lane) * 8;
    const size_t om = ((size_t)(g * 2 + 1) * 64 + lane) * 8;
#pragma unroll
    for (int j = 0; j < 8; j++) { P[oh + j] = h[j]; P[om + j] = m[j]; }
}

// ---------------------------------------------------------------------------
// Fused transpose+split: x[B,Cin,HW] fp32 -> xT hi/lo fp16 [B,HW,Cin],
// all 3 levels in one launch. Grid B*1792 x 256.
// ---------------------------------------------------------------------------
__global__ __launch_bounds__(256) void transpose_all(
    const float* __restrict__ x3, const float* __restrict__ x4,
    const float* __restrict__ x5,
    _Float16* __restrict__ xh3, _Float16* __restrict__ xm3,
    _Float16* __restrict__ xh4, _Float16* __restrict__ xm4,
    _Float16* __restrict__ xh5, _Float16* __restrict__ xm5, int B)
{
    __shared__ float T[32][33];
    const int bid = blockIdx.x;
    const int n3 = 128 * 8 * B, n4 = 32 * 16 * B;
    const float* x; _Float16 *xh, *xm; int Cin, HW, pb, cb, b;
    if (bid < n3)           { x = x3; xh = xh3; xm = xm3; Cin = 256;  HW = 4096;
                              pb = bid % 128; cb = (bid / 128) % 8;  b = bid / (128 * 8); }
    else if (bid < n3 + n4) { const int l = bid - n3; x = x4; xh = xh4; xm = xm4; Cin = 512; HW = 1024;
                              pb = l % 32;  cb = (l / 32) % 16; b = l / (32 * 16); }
    else                    { const int l = bid - n3 - n4; x = x5; xh = xh5; xm = xm5; Cin = 1024; HW = 256;
                              pb = l % 8;   cb = (l / 8) % 32;  b = l / (8 * 32); }
    const int p0 = pb * 32, c0 = cb * 32;
    const int t = threadIdx.x;
    const int pl = t & 31, cl = t >> 5;
    const float* xb = x + (size_t)b * Cin * HW;
#pragma unroll
    for (int rep = 0; rep < 4; rep++)
        T[cl + rep * 8][pl] = xb[(size_t)(c0 + cl + rep * 8) * HW + p0 + pl];
    __syncthreads();
    const int cl2 = t & 31, pl2 = t >> 5;
#pragma unroll
    for (int rep = 0; rep < 4; rep++) {
        const float v = T[cl2][pl2 + rep * 8];
        const _Float16 h = (_Float16)v;
        const _Float16 m = (_Float16)(v - (float)h);
        const size_t o = ((size_t)b * HW + p0 + pl2 + rep * 8) * Cin + c0 + cl2;
        xh[o] = h;
        xm[o] = m;
    }
}

// ---------------------------------------------------------------------------
// Lateral conv + BN via fp16x2 MFMA (3 products: hh, hm, mh).
// Block 512 thr, tile M=64 pixels x N=256 outs. Grid B*84.
// ---------------------------------------------------------------------------
__global__ __launch_bounds__(512) void lateral_mfma(
    const _Float16* __restrict__ xh3, const _Float16* __restrict__ xm3,
    const _Float16* __restrict__ xh4, const _Float16* __restrict__ xm4,
    const _Float16* __restrict__ xh5, const _Float16* __restrict__ xm5,
    const _Float16* __restrict__ w3, const _Float16* __restrict__ w4,
    const _Float16* __restrict__ w5,
    const float* __restrict__ bng, const float* __restrict__ bnb,
    const float* __restrict__ bnm, const float* __restrict__ bnv,
    float* __restrict__ flat, int B)
{
    const int bid = blockIdx.x;
    const int n3 = B * 64, n4 = B * 16;
    const _Float16 *xh, *xm, *wp;
    int CH, HW, base, rb, lv;
    if (bid < n3)            { xh = xh3; xm = xm3; wp = w3; CH = 8;  HW = 4096; base = 0;    rb = bid * 64;             lv = 0; }
    else if (bid < n3 + n4)  { xh = xh4; xm = xm4; wp = w4; CH = 16; HW = 1024; base = 4096; rb = (bid - n3) * 64;      lv = 1; }
    else                     { xh = xh5; xm = xm5; wp = w5; CH = 32; HW = 256;  base = 5120; rb = (bid - n3 - n4) * 64; lv = 2; }
    const int Cin = CH * 32;
    const int b   = rb / HW;
    const int px0 = rb % HW;

    const int t = threadIdx.x, lane = t & 63, w = t >> 6;
    const int ar = lane & 15, quad = lane >> 4;
    const f16x8* BP = (const f16x8*)wp;

    f32x4 acc[4][2];
#pragma unroll
    for (int mt = 0; mt < 4; mt++)
#pragma unroll
        for (int q = 0; q < 2; q++) acc[mt][q] = (f32x4){0.f, 0.f, 0.f, 0.f};

    for (int ks = 0; ks < CH; ks++) {
        const int ao = ks * 32 + quad * 8;
        f16x8 bh[2], bm[2];
#pragma unroll
        for (int q = 0; q < 2; q++) {
            const int g = ks * 16 + (w * 2 + q);
            bh[q] = BP[(g * 2 + 0) * 64 + lane];
            bm[q] = BP[(g * 2 + 1) * 64 + lane];
        }
        f16x8 ah[4], am[4];
#pragma unroll
        for (int mt = 0; mt < 4; mt++) {
            const size_t off = (size_t)(rb + ar + mt * 16) * Cin + ao;
            ah[mt] = *(const f16x8*)&xh[off];
            am[mt] = *(const f16x8*)&xm[off];
        }
#pragma unroll
        for (int q = 0; q < 2; q++)
#pragma unroll
            for (int mt = 0; mt < 4; mt++)
                acc[mt][q] = __builtin_amdgcn_mfma_f32_16x16x32_f16(ah[mt], bh[q], acc[mt][q], 0, 0, 0);
#pragma unroll
        for (int q = 0; q < 2; q++)
#pragma unroll
            for (int mt = 0; mt < 4; mt++)
                acc[mt][q] = __builtin_amdgcn_mfma_f32_16x16x32_f16(ah[mt], bm[q], acc[mt][q], 0, 0, 0);
#pragma unroll
        for (int q = 0; q < 2; q++)
#pragma unroll
            for (int mt = 0; mt < 4; mt++)
                acc[mt][q] = __builtin_amdgcn_mfma_f32_16x16x32_f16(am[mt], bh[q], acc[mt][q], 0, 0, 0);
    }

#pragma unroll
    for (int q = 0; q < 2; q++) {
        const int col = (w * 2 + q) * 16 + ar;
        const float sc = bng[lv * 256 + col] * rsqrtf(bnv[lv * 256 + col] + LN_EPS);
        const float mh = bnm[lv * 256 + col];
        const float bb = bnb[lv * 256 + col];
#pragma unroll
        for (int mt = 0; mt < 4; mt++)
#pragma unroll
            for (int r = 0; r < 4; r++) {
                const int lr = mt * 16 + quad * 4 + r;
                flat[((size_t)b * 5376 + base + px0 + lr) * 256 + col] =
                    (acc[mt][q][r] - mh) * sc + bb;
            }
    }
}

// ---------------------------------------------------------------------------
// Fused loc MLP (fp16x2 MFMA, 3 products): 4 layers + 256->1 projection.
// Grid M/64, block 512 (8 waves).
// ---------------------------------------------------------------------------
__global__ __launch_bounds__(512) void loc_mlp_f16(
    const float* __restrict__ Xin,
    const _Float16* __restrict__ Wpk,
    const float* __restrict__ bs, const float* __restrict__ lng,
    const float* __restrict__ lnb, const float* __restrict__ Wf,
    const float* __restrict__ bfp, float* __restrict__ logits)
{
    __shared__ _Float16 Xh[64 * XS2];
    __shared__ _Float16 Xm[64 * XS2];
    __shared__ float red[2 * 64 * 8];    // [plane][row][wave]
    const int t = threadIdx.x, lane = t & 63, w = t >> 6;
    const int r0 = blockIdx.x * 64;
    const f16x8* BP = (const f16x8*)Wpk;

    const float* Xg = Xin + (size_t)r0 * 256;
#pragma unroll
    for (int i = 0; i < 8; i++) {
        const int f = i * 2048 + t * 4;
        const int row = f >> 8, col = f & 255;
        const f32x4 v = __builtin_nontemporal_load((const f32x4*)&Xg[f]);
        f16x4 h, m;
        h[0] = (_Float16)v[0]; m[0] = (_Float16)(v[0] - (float)h[0]);
        h[1] = (_Float16)v[1]; m[1] = (_Float16)(v[1] - (float)h[1]);
        h[2] = (_Float16)v[2]; m[2] = (_Float16)(v[2] - (float)h[2]);
        h[3] = (_Float16)v[3]; m[3] = (_Float16)(v[3] - (float)h[3]);
        *(f16x4*)&Xh[row * XS2 + col] = h;
        *(f16x4*)&Xm[row * XS2 + col] = m;
    }

    f32x4 acc[4][2];
    float mean[4][4], rstd[4][4];
    const int ar = lane & 15, quad = lane >> 4;

    for (int l = 0; l < 4; l++) {
        __syncthreads();
#pragma unroll
        for (int mt = 0; mt < 4; mt++)
#pragma unroll
            for (int q = 0; q < 2; q++) acc[mt][q] = (f32x4){0.f, 0.f, 0.f, 0.f};
#pragma unroll
        for (int ks = 0; ks < 8; ks++) {
            const int ao = ks * 32 + quad * 8;
            f16x8 bh[2], bm[2];
#pragma unroll
            for (int q = 0; q < 2; q++) {
                const int g = (l * 8 + ks) * 16 + (w * 2 + q);
                bh[q] = BP[(g * 2 + 0) * 64 + lane];
                bm[q] = BP[(g * 2 + 1) * 64 + lane];
            }
            f16x8 ah[4], am[4];
#pragma unroll
            for (int mt = 0; mt < 4; mt++) {
                ah[mt] = *(const f16x8*)&Xh[(ar + mt * 16) * XS2 + ao];
                am[mt] = *(const f16x8*)&Xm[(ar + mt * 16) * XS2 + ao];
            }
#pragma unroll
            for (int q = 0; q < 2; q++)
#pragma unroll
                for (int mt = 0; mt < 4; mt++)
                    acc[mt][q] = __builtin_amdgcn_mfma_f32_16x16x32_f16(ah[mt], bh[q], acc[mt][q], 0, 0, 0);
#pragma unroll
            for (int q = 0; q < 2; q++)
#pragma unroll
                for (int mt = 0; mt < 4; mt++)
                    acc[mt][q] = __builtin_amdgcn_mfma_f32_16x16x32_f16(ah[mt], bm[q], acc[mt][q], 0, 0, 0);
#pragma unroll
            for (int q = 0; q < 2; q++)
#pragma unroll
                for (int mt = 0; mt < 4; mt++)
                    acc[mt][q] = __builtin_amdgcn_mfma_f32_16x16x32_f16(am[mt], bh[q], acc[mt][q], 0, 0, 0);
        }

        float bcol[2];
#pragma unroll
        for (int q = 0; q < 2; q++) bcol[q] = bs[l * 256 + (w * 2 + q) * 16 + ar];
#pragma unroll
        for (int mt = 0; mt < 4; mt++)
#pragma unroll
            for (int q = 0; q < 2; q++)
#pragma unroll
                for (int r = 0; r < 4; r++) acc[mt][q][r] += bcol[q];

#pragma unroll
        for (int mt = 0; mt < 4; mt++)
#pragma unroll
            for (int r = 0; r < 4; r++) {
                float s  = acc[mt][0][r] + acc[mt][1][r];
                float ss = acc[mt][0][r] * acc[mt][0][r] + acc[mt][1][r] * acc[mt][1][r];
#pragma unroll
                for (int off = 1; off < 16; off <<= 1) {
                    s  += __shfl_xor(s, off, 64);
                    ss += __shfl_xor(ss, off, 64);
                }
                if (ar == 0) {
                    const int row = mt * 16 + quad * 4 + r;
                    red[row * 8 + w] = s;
                    red[512 + row * 8 + w] = ss;
                }
            }
        __syncthreads();
#pragma unroll
        for (int mt = 0; mt < 4; mt++)
#pragma unroll
            for (int r = 0; r < 4; r++) {
                const int row = mt * 16 + quad * 4 + r;
                float s = 0.f, ss = 0.f;
#pragma unroll
                for (int q = 0; q < 8; q++) { s += red[row * 8 + q]; ss += red[512 + row * 8 + q]; }
                const float mn = s * (1.0f / 256.0f);
                mean[mt][r] = mn;
                rstd[mt][r] = rsqrtf(ss * (1.0f / 256.0f) - mn * mn + LN_EPS);
            }

        if (l < 3) {
#pragma unroll
            for (int q = 0; q < 2; q++) {
                const int col = (w * 2 + q) * 16 + ar;
                const float gc = lng[l * 256 + col], bc = lnb[l * 256 + col];
#pragma unroll
                for (int mt = 0; mt < 4; mt++)
#pragma unroll
                    for (int r = 0; r < 4; r++) {
                        const int row = mt * 16 + quad * 4 + r;
                        float v = (acc[mt][q][r] - mean[mt][r]) * rstd[mt][r] * gc + bc;
                        v = v * sigmoid_fast(v);
                        const _Float16 h = (_Float16)v;
                        Xh[row * XS2 + col] = h;
                        Xm[row * XS2 + col] = (_Float16)(v - (float)h);
                    }
            }
        } else {
            float p[4][4];
#pragma unroll
            for (int mt = 0; mt < 4; mt++)
#pragma unroll
                for (int r = 0; r < 4; r++) p[mt][r] = 0.0f;
#pragma unroll
            for (int q = 0; q < 2; q++) {
                const int col = (w * 2 + q) * 16 + ar;
                const float gc = lng[3 * 256 + col], bc = lnb[3 * 256 + col];
                const float wf = Wf[col];
#pragma unroll
                for (int mt = 0; mt < 4; mt++)
#pragma unroll
                    for (int r = 0; r < 4; r++) {
                        float v = (acc[mt][q][r] - mean[mt][r]) * rstd[mt][r] * gc + bc;
                        p[mt][r] += (v * sigmoid_fast(v)) * wf;
                    }
            }
            __syncthreads();
#pragma unroll
            for (int mt = 0; mt < 4; mt++)
#pragma unroll
                for (int r = 0; r < 4; r++) {
                    float s = p[mt][r];
#pragma unroll
                    for (int off = 1; off < 16; off <<= 1) s += __shfl_xor(s, off, 64);
                    if (ar == 0) red[(mt * 16 + quad * 4 + r) * 8 + w] = s;
                }
            __syncthreads();
            if (t < 64) {
                float s = 0.f;
#pragma unroll
                for (int q = 0; q < 8; q++) s += red[t * 8 + q];
                logits[r0 + t] = s + bfp[0];
            }
        }
    }
}

// ---------------------------------------------------------------------------
// Top-100 per batch (sorted desc, ties -> lower index). Grid B, block 256.
// ---------------------------------------------------------------------------
__global__ __launch_bounds__(256) void topk_kernel(
    const float* __restrict__ logits, int* __restrict__ idx_out,
    float* __restrict__ out, int B)
{
    __shared__ float v[5376];
    __shared__ float wv_s[4];
    __shared__ int wi_s[4];

    const int t = threadIdx.x, b = blockIdx.x;
    const int lane = t & 63, w = t >> 6;

    for (int i = t; i < 5376; i += 256) v[i] = logits[b * 5376 + i];
    __syncthreads();

    int cnt = 0;
    for (int k = 0; k < 100; k++) {
        float bv = -1e30f;
        int bi = 0x7fffffff;
        for (int i = t; i < 5376; i += 256) {
            const float val = v[i];
            if (val > bv) { bv = val; bi = i; }
        }
#pragma unroll
        for (int off = 32; off > 0; off >>= 1) {
            const float ov = __shfl_xor(bv, off, 64);
            const int oi = __shfl_xor(bi, off, 64);
            if (ov > bv || (ov == bv && oi < bi)) { bv = ov; bi = oi; }
        }
        if (lane == 0) { wv_s[w] = bv; wi_s[w] = bi; }
        __syncthreads();
        if (t == 0) {
            float fb = wv_s[0]; int fi = wi_s[0];
            for (int q = 1; q < 4; q++)
                if (wv_s[q] > fb || (wv_s[q] == fb && wi_s[q] < fi)) { fb = wv_s[q]; fi = wi_s[q]; }
            v[fi] = -1e30f;
            idx_out[b * 100 + k] = fi;
            out[B + b * 100 + k] = sigmoidf(fb);
            if (fb > 0.0f) cnt++;
        }
        __syncthreads();
    }
    if (t == 0) out[b] = (float)cnt;
}

// ---------------------------------------------------------------------------
// Fused heads on the fp16x2 MFMA core (4 products for max margin):
// gather + 4x [GEMM+LN+SiLU] + finals. Grid (ceil(R/64), 2), block 512.
// ---------------------------------------------------------------------------
__global__ __launch_bounds__(512) void heads_mlp_f16(
    const float* __restrict__ flat, const int* __restrict__ idxb,
    const _Float16* __restrict__ cWpk, const float* __restrict__ cbs,
    const float* __restrict__ cg, const float* __restrict__ cb,
    const float* __restrict__ cWf, const float* __restrict__ cbf,
    const _Float16* __restrict__ xWpk, const float* __restrict__ xbs,
    const float* __restrict__ xg, const float* __restrict__ xb_,
    const float* __restrict__ xWf, const float* __restrict__ xbf,
    const int* __restrict__ full_h, const int* __restrict__ full_w,
    float* __restrict__ out, int B, int R)
{
    __shared__ _Float16 Xh[64 * XS2];
    __shared__ _Float16 Xm[64 * XS2];
    __shared__ float red[2 * 64 * 8];
    const int head = blockIdx.y;
    const _Float16* Wpk = head ? xWpk : cWpk;
    const float* bsv = head ? xbs : cbs;
    const float* gv_ = head ? xg : cg;
    const float* bv_ = head ? xb_ : cb;

    const int t = threadIdx.x, lane = t & 63, w = t >> 6;
    const int r0 = blockIdx.x * 64;
    const f16x8* BP = (const f16x8*)Wpk;

    // gather + fp16x2 split staging
#pragma unroll
    for (int i = 0; i < 8; i++) {
        const int f = i * 2048 + t * 4;
        const int row = f >> 8, col = f & 255;
        const int r = min(r0 + row, R - 1);
        const int n = idxb[r];
        const int b = r / 100;
        const f32x4 v = *(const f32x4*)&flat[((size_t)b * 5376 + n) * 256 + col];
        f16x4 h, m;
        h[0] = (_Float16)v[0]; m[0] = (_Float16)(v[0] - (float)h[0]);
        h[1] = (_Float16)v[1]; m[1] = (_Float16)(v[1] - (float)h[1]);
        h[2] = (_Float16)v[2]; m[2] = (_Float16)(v[2] - (float)h[2]);
        h[3] = (_Float16)v[3]; m[3] = (_Float16)(v[3] - (float)h[3]);
        *(f16x4*)&Xh[row * XS2 + col] = h;
        *(f16x4*)&Xm[row * XS2 + col] = m;
    }

    f32x4 acc[4][2];
    float mean[4][4], rstd[4][4];
    const int ar = lane & 15, quad = lane >> 4;

    for (int l = 0; l < 4; l++) {
        __syncthreads();
#pragma unroll
        for (int mt = 0; mt < 4; mt++)
#pragma unroll
            for (int q = 0; q < 2; q++) acc[mt][q] = (f32x4){0.f, 0.f, 0.f, 0.f};
#pragma unroll
        for (int ks = 0; ks < 8; ks++) {
            const int ao = ks * 32 + quad * 8;
            f16x8 bh[2], bm[2];
#pragma unroll
            for (int q = 0; q < 2; q++) {
                const int g = (l * 8 + ks) * 16 + (w * 2 + q);
                bh[q] = BP[(g * 2 + 0) * 64 + lane];
                bm[q] = BP[(g * 2 + 1) * 64 + lane];
            }
            f16x8 ah[4], am[4];
#pragma unroll
            for (int mt = 0; mt < 4; mt++) {
                ah[mt] = *(const f16x8*)&Xh[(ar + mt * 16) * XS2 + ao];
                am[mt] = *(const f16x8*)&Xm[(ar + mt * 16) * XS2 + ao];
            }
#pragma unroll
            for (int q = 0; q < 2; q++)
#pragma unroll
                for (int mt = 0; mt < 4; mt++)
                    acc[mt][q] = __builtin_amdgcn_mfma_f32_16x16x32_f16(ah[mt], bh[q], acc[mt][q], 0, 0, 0);
#pragma unroll
            for (int q = 0; q < 2; q++)
#pragma unroll
                for (int mt = 0; mt < 4; mt++)
                    acc[mt][q] = __builtin_amdgcn_mfma_f32_16x16x32_f16(ah[mt], bm[q], acc[mt][q], 0, 0, 0);
#pragma unroll
            for (int q = 0; q < 2; q++)
#pragma unroll
                for (int mt = 0; mt < 4; mt++)
                    acc[mt][q] = __builtin_amdgcn_mfma_f32_16x16x32_f16(am[mt], bh[q], acc[mt][q], 0, 0, 0);
#pragma unroll
            for (int q = 0; q < 2; q++)
#pragma unroll
                for (int mt = 0; mt < 4; mt++)
                    acc[mt][q] = __builtin_amdgcn_mfma_f32_16x16x32_f16(am[mt], bm[q], acc[mt][q], 0, 0, 0);
        }

        float bcol[2];
#pragma unroll
        for (int q = 0; q < 2; q++) bcol[q] = bsv[l * 256 + (w * 2 + q) * 16 + ar];
#pragma unroll
        for (int mt = 0; mt < 4; mt++)
#pragma unroll
            for (int q = 0; q < 2; q++)
#pragma unroll
                for (int r = 0; r < 4; r++) acc[mt][q][r] += bcol[q];

#pragma unroll
        for (int mt = 0; mt < 4; mt++)
#pragma unroll
            for (int r = 0; r < 4; r++) {
                float s  = acc[mt][0][r] + acc[mt][1][r];
                float ss = acc[mt][0][r] * acc[mt][0][r] + acc[mt][1][r] * acc[mt][1][r];
#pragma unroll
                for (int off = 1; off < 16; off <<= 1) {
                    s  += __shfl_xor(s, off, 64);
                    ss += __shfl_xor(ss, off, 64);
                }
                if (ar == 0) {
                    const int row = mt * 16 + quad * 4 + r;
                    red[row * 8 + w] = s;
                    red[512 + row * 8 + w] = ss;
                }
            }
        __syncthreads();
#pragma unroll
        for (int mt = 0; mt < 4; mt++)
#pragma unroll
            for (int r = 0; r < 4; r++) {
                const int row = mt * 16 + quad * 4 + r;
                float s = 0.f, ss = 0.f;
#pragma unroll
                for (int q = 0; q < 8; q++) { s += red[row * 8 + q]; ss += red[512 + row * 8 + q]; }
                const float mn = s * (1.0f / 256.0f);
                mean[mt][r] = mn;
                rstd[mt][r] = rsqrtf(ss * (1.0f / 256.0f) - mn * mn + LN_EPS);
            }

#pragma unroll
        for (int q = 0; q < 2; q++) {
            const int col = (w * 2 + q) * 16 + ar;
            const float gc = gv_[l * 256 + col], bc = bv_[l * 256 + col];
#pragma unroll
            for (int mt = 0; mt < 4; mt++)
#pragma unroll
                for (int r = 0; r < 4; r++) {
                    const int row = mt * 16 + quad * 4 + r;
                    float v = (acc[mt][q][r] - mean[mt][r]) * rstd[mt][r] * gc + bc;
                    v = v * sigmoid_fast(v);
                    const _Float16 h = (_Float16)v;
                    Xh[row * XS2 + col] = h;
                    Xm[row * XS2 + col] = (_Float16)(v - (float)h);
                }
        }
    }
    __syncthreads();   // finals use cross-wave row mapping

    const int m = t >> 3, g = t & 7;
    const int r = r0 + m;
    if (head == 0) {
        const int jbase = g * 10;
        float lg[10];
#pragma unroll
        for (int jj = 0; jj < 10; jj++) lg[jj] = cbf[jbase + jj];
        for (int k = 0; k < 256; k++) {
            const float hv = (float)Xh[m * XS2 + k] + (float)Xm[m * XS2 + k];
            const float* wr = &cWf[k * 80 + jbase];
#pragma unroll
            for (int jj = 0; jj < 10; jj++) lg[jj] += hv * wr[jj];
        }
        float best = lg[0]; int bj = jbase;
#pragma unroll
        for (int jj = 1; jj < 10; jj++)
            if (lg[jj] > best) { best = lg[jj]; bj = jbase + jj; }
#pragma unroll
        for (int off = 1; off < 8; off <<= 1) {
            const float ob = __shfl_xor(best, off, 64);
            const int oj = __shfl_xor(bj, off, 64);
            if (ob > best || (ob == best && oj < bj)) { best = ob; bj = oj; }
        }
        if (g == 0 && r < R) out[B + B * 100 + r] = (float)bj;
    } else {
        float a[4] = {0.f, 0.f, 0.f, 0.f};
#pragma unroll
        for (int k4 = 0; k4 < 8; k4++) {
            const int kb = g * 32 + k4 * 4;
#pragma unroll
            for (int j = 0; j < 4; j++) {
                const float hv = (float)Xh[m * XS2 + kb + j] + (float)Xm[m * XS2 + kb + j];
                const float4 wf = *(const float4*)&xWf[(kb + j) * 4];
                a[0] += hv * wf.x; a[1] += hv * wf.y;
                a[2] += hv * wf.z; a[3] += hv * wf.w;
            }
        }
#pragma unroll
        for (int off = 1; off < 8; off <<= 1) {
            a[0] += __shfl_xor(a[0], off, 64);
            a[1] += __shfl_xor(a[1], off, 64);
            a[2] += __shfl_xor(a[2], off, 64);
            a[3] += __shfl_xor(a[3], off, 64);
        }
        if (g == 0 && r < R) {
            const float e0 = a[0] + xbf[0], e1 = a[1] + xbf[1];
            const float e2 = a[2] + xbf[2], e3 = a[3] + xbf[3];
            const int n = idxb[r];
            int base, gw, gh;
            if (n < 4096)      { base = 0;    gw = 64; gh = 64; }
            else if (n < 5120) { base = 4096; gw = 32; gh = 32; }
            else               { base = 5120; gw = 16; gh = 16; }
            const int p = n - base;
            const int py = p / gw, px = p % gw;
            const float gx = (px + 0.5f) / gw;
            const float gy = (py + 0.5f) / gh;
            const float fw = (float)full_w[0], fh = (float)full_h[0];
            const int ob = B + 2 * B * 100;
            out[ob + r * 4 + 0] = (gx - 0.5f / gw * expf(e0)) * fw;
            out[ob + r * 4 + 1] = (gy - 0.5f / gh * expf(e1)) * fh;
            out[ob + r * 4 + 2] = (gx + 0.5f / gw * expf(e2)) * fw;
            out[ob + r * 4 + 3] = (gy + 0.5f / gh * expf(e3)) * fh;
        }
    }
}

extern "C" void kernel_launch(void* const* d_in, const int* in_sizes, int n_in,
                              void* d_out, int out_size, void* d_ws, size_t ws_size,
                              hipStream_t stream)
{
    const float* x3  = (const float*)d_in[0];
    const float* x4  = (const float*)d_in[1];
    const float* x5  = (const float*)d_in[2];
    const float* lw3 = (const float*)d_in[3];
    const float* lw4 = (const float*)d_in[4];
    const float* lw5 = (const float*)d_in[5];
    const float* bng = (const float*)d_in[6];
    const float* bnb = (const float*)d_in[7];
    const float* bnm = (const float*)d_in[8];
    const float* bnv = (const float*)d_in[9];

    const float* loc_Ws  = (const float*)d_in[10];
    const float* loc_bs  = (const float*)d_in[11];
    const float* loc_lng = (const float*)d_in[12];
    const float* loc_lnb = (const float*)d_in[13];
    const float* loc_Wf  = (const float*)d_in[14];
    const float* loc_bf  = (const float*)d_in[15];

    const float* cls_Ws  = (const float*)d_in[16];
    const float* cls_bs  = (const float*)d_in[17];
    const float* cls_lng = (const float*)d_in[18];
    const float* cls_lnb = (const float*)d_in[19];
    const float* cls_Wf  = (const float*)d_in[20];
    const float* cls_bf  = (const float*)d_in[21];

    const float* box_Ws  = (const float*)d_in[22];
    const float* box_bs  = (const float*)d_in[23];
    const float* box_lng = (const float*)d_in[24];
    const float* box_lnb = (const float*)d_in[25];
    const float* box_Wf  = (const float*)d_in[26];
    const float* box_bf  = (const float*)d_in[27];

    const int* full_h = (const int*)d_in[28];
    const int* full_w = (const int*)d_in[29];

    const int B = in_sizes[0] / (256 * 64 * 64);   // 8
    const int M = B * 5376;                        // 43008
    const int R = B * 100;                         // 800

    float* ws = (float*)d_ws;
    float* flat = ws;                                  // [M*256] fp32
    float* loc  = flat + (size_t)M * 256;              // [M]
    int*   idxb = (int*)(loc + M);                     // [R] (padded 1024)
    _Float16* locP = (_Float16*)(idxb + 1024);         // 1 MB each
    _Float16* clsP = locP + 524288;
    _Float16* boxP = clsP + 524288;
    _Float16* w3   = boxP + 524288;                    // 256KB
    _Float16* w4   = w3 + 131072;                      // 512KB
    _Float16* w5   = w4 + 262144;                      // 1MB
    _Float16* xh3  = w5 + 524288;
    _Float16* xm3  = xh3 + (size_t)B * 4096 * 256;
    _Float16* xh4  = xm3 + (size_t)B * 4096 * 256;
    _Float16* xm4  = xh4 + (size_t)B * 1024 * 512;
    _Float16* xh5  = xm4 + (size_t)B * 1024 * 512;
    _Float16* xm5  = xh5 + (size_t)B * 256 * 1024;

    float* out = (float*)d_out;
    const dim3 blk(256);

    // 0) all weight prep (1 launch) + all activation transposes (1 launch)
    prep_all<<<608, blk, 0, stream>>>(loc_Ws, cls_Ws, box_Ws, lw3, lw4, lw5,
                                      locP, clsP, boxP, w3, w4, w5);
    transpose_all<<<B * 1792, blk, 0, stream>>>(x3, x4, x5,
                                                xh3, xm3, xh4, xm4, xh5, xm5, B);

    // 1) laterals (fp16x2 MFMA, 3 products) -> flat
    lateral_mfma<<<B * 84, dim3(512), 0, stream>>>(
        xh3, xm3, xh4, xm4, xh5, xm5, w3, w4, w5,
        bng, bnb, bnm, bnv, flat, B);

    // 2) fused loc MLP (fp16x2 MFMA, 3 products) -> logits
    loc_mlp_f16<<<M / 64, dim3(512), 0, stream>>>(flat, locP, loc_bs,
                                                  loc_lng, loc_lnb, loc_Wf, loc_bf, loc);

    // 3) top-k
    topk_kernel<<<B, blk, 0, stream>>>(loc, idxb, out, B);

    // 4) both heads (fp16x2 MFMA core, 4 products)
    heads_mlp_f16<<<dim3((R + 63) / 64, 2), dim3(512), 0, stream>>>(
        flat, idxb,
        clsP, cls_bs, cls_lng, cls_lnb, cls_Wf, cls_bf,
        boxP, box_bs, box_lng, box_lnb, box_Wf, box_bf,
        full_h, full_w, out, B, R);
}